// Round 8
// baseline (373.878 us; speedup 1.0000x reference)
//
#include <hip/hip_runtime.h>
#include <math.h>

#define H 16
#define B 4
#define S 1024
#define E 1024
#define DK 64

typedef _Float16 f16x8 __attribute__((ext_vector_type(8)));
typedef _Float16 f16x4 __attribute__((ext_vector_type(4)));
typedef float    f32x4 __attribute__((ext_vector_type(4)));

// XOR-swizzle for [r][64 f16] tiles (128B row stride) — reg-staged LDS only.
__device__ __forceinline__ int swzb(int row, int colByte) {
    return row * 128 + (colByte ^ ((row & 7) << 4));
}

// ---------------------------------------------------------------------------
// prep: merged input conversion (one launch instead of two).
// bid < 2048:  emb f32 -> embH/embL (double-f16 split), 8 elems/thread.
// bid >= 2048: weight conversion (et = idx&15, cy = idx>>4):
//   cy<48: Wq/Wk/Wv [h][e][d] -> WTh [n][e] (+WTl n<2048), transposed+split.
//   cy>=48: Wo [k][n] -> WoT [n][k] f16.
// ---------------------------------------------------------------------------
__global__ __launch_bounds__(256) void prep(
    const float* __restrict__ emb,
    const float* __restrict__ Wq, const float* __restrict__ Wk,
    const float* __restrict__ Wv, const float* __restrict__ Wo,
    _Float16* __restrict__ embH, _Float16* __restrict__ embL,
    _Float16* __restrict__ WTh, _Float16* __restrict__ WTl,
    _Float16* __restrict__ WoT) {
    __shared__ _Float16 Th[64 * 64];
    __shared__ _Float16 Tl[64 * 64];
    int bid = blockIdx.x, tid = threadIdx.x;
    if (bid < 2048) {
        int i = (bid * 256 + tid) * 8;
        float4 a = *(const float4*)&emb[i];
        float4 bb = *(const float4*)&emb[i + 4];
        float x[8] = {a.x, a.y, a.z, a.w, bb.x, bb.y, bb.z, bb.w};
        f16x8 hv, lv;
        #pragma unroll
        for (int j = 0; j < 8; ++j) {
            _Float16 hh = (_Float16)x[j];
            hv[j] = hh;
            lv[j] = (_Float16)(x[j] - (float)hh);
        }
        *(f16x8*)&embH[i] = hv;
        *(f16x8*)&embL[i] = lv;
        return;
    }
    int idx = bid - 2048;
    int et = idx & 15, cy = idx >> 4;
    if (cy < 48) {
        const float* W = (cy < 16 ? Wq : cy < 32 ? Wk : Wv)
                         + (size_t)(cy & 15) * E * DK;
        #pragma unroll
        for (int rr = 0; rr < 4; ++rr) {
            int u = rr * 256 + tid;
            int ei = u >> 4, f4 = u & 15;
            float4 v = *(const float4*)&W[(size_t)(et * 64 + ei) * 64 + f4 * 4];
            float x[4] = {v.x, v.y, v.z, v.w};
            f16x4 h, l;
            #pragma unroll
            for (int j = 0; j < 4; ++j) {
                _Float16 hh = (_Float16)x[j];
                h[j] = hh;
                l[j] = (_Float16)(x[j] - (float)hh);
            }
            *(f16x4*)((char*)Th + swzb(ei, f4 * 8)) = h;
            *(f16x4*)((char*)Tl + swzb(ei, f4 * 8)) = l;
        }
        __syncthreads();
        #pragma unroll
        for (int rr = 0; rr < 2; ++rr) {
            int u = rr * 256 + tid;
            int d = u >> 3, e8 = u & 7;
            f16x8 oh, ol;
            #pragma unroll
            for (int j = 0; j < 8; ++j) {
                int ei = e8 * 8 + j;
                oh[j] = *(_Float16*)((char*)Th + swzb(ei, d * 2));
                ol[j] = *(_Float16*)((char*)Tl + swzb(ei, d * 2));
            }
            size_t o = (size_t)(cy * 64 + d) * 1024 + et * 64 + e8 * 8;
            *(f16x8*)&WTh[o] = oh;
            if (cy < 32) *(f16x8*)&WTl[o] = ol;
        }
    } else {
        int kt = et, nt = cy - 48;
        #pragma unroll
        for (int rr = 0; rr < 4; ++rr) {
            int u = rr * 256 + tid;
            int ki = u >> 4, f4 = u & 15;
            float4 v = *(const float4*)&Wo[(size_t)(kt * 64 + ki) * 1024 + nt * 64 + f4 * 4];
            f16x4 o = { (_Float16)v.x, (_Float16)v.y, (_Float16)v.z, (_Float16)v.w };
            *(f16x4*)((char*)Th + swzb(ki, f4 * 8)) = o;
        }
        __syncthreads();
        #pragma unroll
        for (int rr = 0; rr < 2; ++rr) {
            int u = rr * 256 + tid;
            int nl = u >> 3, k8 = u & 7;
            f16x8 o;
            #pragma unroll
            for (int j = 0; j < 8; ++j) {
                int ki = k8 * 8 + j;
                o[j] = *(_Float16*)((char*)Th + swzb(ki, nl * 2));
            }
            *(f16x8*)&WoT[(size_t)(nt * 64 + nl) * 1024 + kt * 64 + k8 * 8] = o;
        }
    }
}

// ---------------------------------------------------------------------------
// Fused QKV projection. grid 768 = 32 mt x 24 nt, XCD-bijective decode.
// nt<16: Q,K double-f16 (3-term MFMA), BK=32, linear LDS (r7 gemm_qk body).
// nt>=16: V single-term, BK=64, linear LDS (r7 gemm_v body).
// One launch instead of two (gap removal); NO source swizzle (r6 lesson).
// ---------------------------------------------------------------------------
__global__ __launch_bounds__(256) void gemm_qkv(
    const _Float16* __restrict__ AH, const _Float16* __restrict__ AL,
    const _Float16* __restrict__ BTh, const _Float16* __restrict__ BTl,
    _Float16* __restrict__ QbH, _Float16* __restrict__ QbL,
    _Float16* __restrict__ kkTH, _Float16* __restrict__ kkTL,
    _Float16* __restrict__ V2) {
    __shared__ _Float16 SA[128 * 64];   // QK: H half [0,4096), L half [4096,8192)
    __shared__ _Float16 SB[128 * 64];
    int wg = ((int)blockIdx.x & 7) * 96 + ((int)blockIdx.x >> 3);
    int mt = wg / 24, nt = wg % 24;
    int r0 = mt * 128;
    int tid = threadIdx.x, lane = tid & 63, w = tid >> 6;
    int wr = w >> 1, wc = w & 1;
    int l15 = lane & 15, l4 = lane >> 4;

    f32x4 zero = {0.f, 0.f, 0.f, 0.f};
    f32x4 acc[4][4];
    #pragma unroll
    for (int i = 0; i < 4; ++i)
        #pragma unroll
        for (int j = 0; j < 4; ++j) acc[i][j] = zero;

    if (nt < 16) {
        // ---------------- Q,K path (double-f16, BK=32) ----------------
        int c0 = nt * 128;
        for (int kt = 0; kt < 32; ++kt) {
            __syncthreads();
            #pragma unroll
            for (int rr = 0; rr < 2; ++rr) {
                int u = rr * 256 + tid;
                int row = u >> 2, c8 = u & 3;
                size_t ga = (size_t)(r0 + row) * 1024 + kt * 32 + c8 * 8;
                size_t gb = (size_t)(c0 + row) * 1024 + kt * 32 + c8 * 8;
                __builtin_amdgcn_global_load_lds(&AH[ga],  &SA[u * 8], 16, 0, 0);
                __builtin_amdgcn_global_load_lds(&AL[ga],  &SA[4096 + u * 8], 16, 0, 0);
                __builtin_amdgcn_global_load_lds(&BTh[gb], &SB[u * 8], 16, 0, 0);
                __builtin_amdgcn_global_load_lds(&BTl[gb], &SB[4096 + u * 8], 16, 0, 0);
            }
            __syncthreads();

            int kb = l4 * 16;
            f16x8 afH[4], afL[4], bfH[4], bfL[4];
            #pragma unroll
            for (int f = 0; f < 4; ++f) {
                int ar = wr * 64 + f * 16 + l15;
                int br = wc * 64 + f * 16 + l15;
                afH[f] = *(const f16x8*)((char*)SA + ar * 64 + kb);
                afL[f] = *(const f16x8*)((char*)SA + 8192 + ar * 64 + kb);
                bfH[f] = *(const f16x8*)((char*)SB + br * 64 + kb);
                bfL[f] = *(const f16x8*)((char*)SB + 8192 + br * 64 + kb);
            }
            #pragma unroll
            for (int i = 0; i < 4; ++i)
                #pragma unroll
                for (int j = 0; j < 4; ++j) {
                    acc[i][j] = __builtin_amdgcn_mfma_f32_16x16x32_f16(
                        afH[i], bfH[j], acc[i][j], 0, 0, 0);
                    acc[i][j] = __builtin_amdgcn_mfma_f32_16x16x32_f16(
                        afH[i], bfL[j], acc[i][j], 0, 0, 0);
                    acc[i][j] = __builtin_amdgcn_mfma_f32_16x16x32_f16(
                        afL[i], bfH[j], acc[i][j], 0, 0, 0);
                }
        }

        #pragma unroll
        for (int i = 0; i < 4; ++i) {
            int grow0 = r0 + wr * 64 + i * 16 + l4 * 4;
            #pragma unroll
            for (int j = 0; j < 4; ++j) {
                int gcol = c0 + wc * 64 + j * 16 + l15;
                if (gcol < 1024) {                       // ---- Q (split) ----
                    int hh = gcol >> 6, dk = gcol & 63;
                    #pragma unroll
                    for (int r = 0; r < 4; ++r) {
                        int grow = grow0 + r;
                        int bb = grow >> 10, s = grow & 1023;
                        float v = acc[i][j][r];
                        _Float16 hq = (_Float16)v;
                        size_t o = (((size_t)hh * 4 + bb) * 1024 + s) * 64 + dk;
                        QbH[o] = hq;
                        QbL[o] = (_Float16)(v - (float)hq);
                    }
                } else {                                 // ---- K (split, reshaped) ----
                    int hh = (gcol >> 6) & 15, dk = gcol & 63;
                    #pragma unroll
                    for (int r = 0; r < 4; ++r) {
                        int grow = grow0 + r;
                        int bb = grow >> 10, s = grow & 1023;
                        float v = acc[i][j][r];
                        _Float16 hq = (_Float16)v;
                        size_t o = (((size_t)hh * 4 + bb) * 64 + (s >> 4)) * 1024
                                   + (s & 15) * 64 + dk;
                        kkTH[o] = hq;
                        kkTL[o] = (_Float16)(v - (float)hq);
                    }
                }
            }
        }
    } else {
        // ---------------- V path (single f16, BK=64) ----------------
        int c0 = (nt - 16) * 128;            // V2 columns; weights at 2048+c0
        for (int kt = 0; kt < 16; ++kt) {
            __syncthreads();
            #pragma unroll
            for (int rr = 0; rr < 4; ++rr) {
                int u = rr * 256 + tid;
                int row = u >> 3, c8 = u & 7;
                size_t ga = (size_t)(r0 + row) * 1024 + kt * 64 + c8 * 8;
                size_t gb = (size_t)(2048 + c0 + row) * 1024 + kt * 64 + c8 * 8;
                __builtin_amdgcn_global_load_lds(&AH[ga],  &SA[u * 8], 16, 0, 0);
                __builtin_amdgcn_global_load_lds(&BTh[gb], &SB[u * 8], 16, 0, 0);
            }
            __syncthreads();

            #pragma unroll
            for (int ks = 0; ks < 2; ++ks) {
                int kb = (ks * 32 + l4 * 8) * 2;
                f16x8 af[4], bf[4];
                #pragma unroll
                for (int f = 0; f < 4; ++f) {
                    int ar = wr * 64 + f * 16 + l15;
                    int br = wc * 64 + f * 16 + l15;
                    af[f] = *(const f16x8*)((char*)SA + ar * 128 + kb);
                    bf[f] = *(const f16x8*)((char*)SB + br * 128 + kb);
                }
                #pragma unroll
                for (int i = 0; i < 4; ++i)
                    #pragma unroll
                    for (int j = 0; j < 4; ++j)
                        acc[i][j] = __builtin_amdgcn_mfma_f32_16x16x32_f16(
                            af[i], bf[j], acc[i][j], 0, 0, 0);
            }
        }

        #pragma unroll
        for (int i = 0; i < 4; ++i) {
            int grow0 = r0 + wr * 64 + i * 16 + l4 * 4;
            int bb = grow0 >> 10, s = grow0 & 1023;
            #pragma unroll
            for (int j = 0; j < 4; ++j) {
                int gcol = c0 + wc * 64 + j * 16 + l15;
                int hh = gcol >> 6, dv = gcol & 63;
                f16x4 o = { (_Float16)acc[i][j][0], (_Float16)acc[i][j][1],
                            (_Float16)acc[i][j][2], (_Float16)acc[i][j][3] };
                *(f16x4*)&V2[(((size_t)hh * 4 + bb) * 64 + dv) * 1024 + s] = o;
            }
        }
    }
}

// ---------------------------------------------------------------------------
// kkT [hb][64 d][1024 t] -> K2 [hb][1024 t][64 d], modes: 0=hi, 1=lo.
// ---------------------------------------------------------------------------
__global__ __launch_bounds__(256) void trans_k(const _Float16* __restrict__ kkTH,
                                               const _Float16* __restrict__ kkTL,
                                               _Float16* __restrict__ K2H,
                                               _Float16* __restrict__ K2L) {
    int tt = blockIdx.x;
    size_t hb = blockIdx.y;
    int mode = blockIdx.z;
    const _Float16* src = mode ? kkTL : kkTH;
    _Float16* dst = mode ? K2L : K2H;
    __shared__ _Float16 T[64 * 64];
    int tid = threadIdx.x;
    #pragma unroll
    for (int rr = 0; rr < 2; ++rr) {
        int u = rr * 256 + tid;
        int d = u >> 3, c8 = u & 7;
        f16x8 v = *(const f16x8*)&src[(hb * 64 + d) * 1024 + tt * 64 + c8 * 8];
        *(f16x8*)((char*)T + swzb(d, c8 * 16)) = v;
    }
    __syncthreads();
    #pragma unroll
    for (int rr = 0; rr < 2; ++rr) {
        int u = rr * 256 + tid;
        int ti = u >> 3, d8 = u & 7;
        f16x8 o;
        #pragma unroll
        for (int j = 0; j < 8; ++j)
            o[j] = *(_Float16*)((char*)T + swzb(d8 * 8 + j, ti * 2));
        *(f16x8*)&dst[(hb * 1024 + tt * 64 + ti) * 64 + d8 * 8] = o;
    }
}

// ---------------------------------------------------------------------------
// Flash attention, STAGING-FREE (m169: K/V are L1/L2-resident; staging was
// overhead). No Q/K/V LDS, no __syncthreads — waves fully independent.
// Only Ps (wave-private rows, 8KB) stays in LDS for the P^T->PV hop.
// XCD-pinned decode: 8 hb per XCD -> 3MB K/V per XCD L2 (4MB). LPT via
// reversed qt. Math identical to r7 (same frag addresses, now direct).
// ---------------------------------------------------------------------------
__global__ __launch_bounds__(256) void attn(
    const _Float16* __restrict__ QbH, const _Float16* __restrict__ QbL,
    const _Float16* __restrict__ K2H, const _Float16* __restrict__ K2L,
    const _Float16* __restrict__ V2, _Float16* __restrict__ CC) {
    int bid = blockIdx.x;
    int xcd = bid & 7, slot = bid >> 3;
    int hbi = xcd * 8 + (slot >> 4);       // 8 hb's pinned per XCD
    int qt = 15 - (slot & 15);             // LPT: long blocks first
    int h = hbi >> 2, b = hbi & 3;
    size_t hb = (size_t)hbi;
    __shared__ _Float16 Ps[64 * 64];
    int tid = threadIdx.x, lane = tid & 63, w = tid >> 6;
    int l15 = lane & 15, l4 = lane >> 4;
    int s0 = qt * 64;
    int srow = w * 16 + l15;
    int sg = s0 + srow;

    // Q frags: direct global load (once per wave)
    f16x8 qfH[2], qfL[2];
    #pragma unroll
    for (int ks = 0; ks < 2; ++ks) {
        size_t qa = (hb * 1024 + s0 + srow) * 64 + ks * 32 + l4 * 8;
        qfH[ks] = *(const f16x8*)&QbH[qa];
        qfL[ks] = *(const f16x8*)&QbL[qa];
    }

    float m = -__builtin_inff(), lsum = 0.f;
    f32x4 zero = {0.f, 0.f, 0.f, 0.f};
    f32x4 acc2[4] = {zero, zero, zero, zero};
    int ntile = qt + 1;

    for (int tt = 0; tt < ntile; ++tt) {
        int t0 = tt * 64;
        f32x4 z[4] = {zero, zero, zero, zero};
        __builtin_amdgcn_s_setprio(1);
        #pragma unroll
        for (int ks = 0; ks < 2; ++ks) {
            #pragma unroll
            for (int f = 0; f < 4; ++f) {
                int trow = f * 16 + l15;
                size_t ka = (hb * 1024 + t0 + trow) * 64 + ks * 32 + l4 * 8;
                f16x8 akH = *(const f16x8*)&K2H[ka];
                f16x8 akL = *(const f16x8*)&K2L[ka];
                z[f] = __builtin_amdgcn_mfma_f32_16x16x32_f16(akH, qfH[ks], z[f], 0, 0, 0);
                z[f] = __builtin_amdgcn_mfma_f32_16x16x32_f16(akH, qfL[ks], z[f], 0, 0, 0);
                z[f] = __builtin_amdgcn_mfma_f32_16x16x32_f16(akL, qfH[ks], z[f], 0, 0, 0);
            }
        }
        __builtin_amdgcn_s_setprio(0);
        // scale + causal mask + row max (rows split over 4-lane group l15/16/32/48)
        float mt = -__builtin_inff();
        #pragma unroll
        for (int f = 0; f < 4; ++f)
            #pragma unroll
            for (int r = 0; r < 4; ++r) {
                int tg = t0 + f * 16 + l4 * 4 + r;
                float val = z[f][r] * 0.125f;
                val = (tg > sg) ? -__builtin_inff() : val;
                z[f][r] = val;
                mt = fmaxf(mt, val);
            }
        mt = fmaxf(mt, __shfl_xor(mt, 16));
        mt = fmaxf(mt, __shfl_xor(mt, 32));
        float mn = fmaxf(m, mt);
        float corr = __expf(m - mn);
        float ps = 0.f;
        #pragma unroll
        for (int f = 0; f < 4; ++f)
            #pragma unroll
            for (int r = 0; r < 4; ++r) {
                float p = __expf(z[f][r] - mn);
                z[f][r] = p;
                ps += p;
            }
        ps += __shfl_xor(ps, 16);
        ps += __shfl_xor(ps, 32);
        lsum = lsum * corr + ps;
        m = mn;
        #pragma unroll
        for (int f = 0; f < 4; ++f) acc2[f] *= corr;

        // P^T -> Ps (wave-private rows; within-wave ds ordering only)
        #pragma unroll
        for (int f = 0; f < 4; ++f) {
            f16x4 pk = { (_Float16)z[f][0], (_Float16)z[f][1],
                         (_Float16)z[f][2], (_Float16)z[f][3] };
            *(f16x4*)((char*)Ps + swzb(srow, (f * 16 + l4 * 4) * 2)) = pk;
        }
        __builtin_amdgcn_s_setprio(1);
        #pragma unroll
        for (int ks = 0; ks < 2; ++ks) {
            int kb = (ks * 32 + l4 * 8) * 2;
            f16x8 bp = *(const f16x8*)((char*)Ps + swzb(srow, kb));
            #pragma unroll
            for (int f = 0; f < 4; ++f) {
                int dvrow = f * 16 + l15;
                size_t va = (hb * 64 + dvrow) * 1024 + t0 + ks * 32 + l4 * 8;
                f16x8 av = *(const f16x8*)&V2[va];
                acc2[f] = __builtin_amdgcn_mfma_f32_16x16x32_f16(av, bp, acc2[f], 0, 0, 0);
            }
        }
        __builtin_amdgcn_s_setprio(0);
    }

    float inv = 1.f / lsum;
    int sp = s0 + srow;
    int bprow = h >> 2;
    int spp = (h & 3) * 256 + b * 64 + (sp >> 4);
    int cb = (sp & 15) * 64;
    #pragma unroll
    for (int f = 0; f < 4; ++f) {
        int dv = f * 16 + l4 * 4;
        f16x4 o = { (_Float16)(acc2[f][0] * inv), (_Float16)(acc2[f][1] * inv),
                    (_Float16)(acc2[f][2] * inv), (_Float16)(acc2[f][3] * inv) };
        *(f16x4*)&CC[((size_t)bprow * 1024 + spp) * 1024 + cb + dv] = o;
    }
}

// ---------------------------------------------------------------------------
// Output projection: CC[4096][1024] @ WoT[1024][1024]^T -> out f32.
// m97 structure: 128x128 tile, BK=64, gload_lds, linear LDS.
// ---------------------------------------------------------------------------
__global__ __launch_bounds__(256) void gemm_out(
    const _Float16* __restrict__ A, const _Float16* __restrict__ BT,
    float* __restrict__ out) {
    __shared__ _Float16 As[128 * 64];
    __shared__ _Float16 Bs[128 * 64];
    int wg = ((int)blockIdx.x & 7) * 32 + ((int)blockIdx.x >> 3);
    int mt = wg >> 3, nt = wg & 7;
    int r0 = mt * 128, c0 = nt * 128;
    int tid = threadIdx.x, lane = tid & 63, w = tid >> 6;
    int wr = w >> 1, wc = w & 1;
    int l15 = lane & 15, l4 = lane >> 4;

    f32x4 zero = {0.f, 0.f, 0.f, 0.f};
    f32x4 acc[4][4];
    #pragma unroll
    for (int i = 0; i < 4; ++i)
        #pragma unroll
        for (int j = 0; j < 4; ++j) acc[i][j] = zero;

    for (int kt = 0; kt < 16; ++kt) {
        __syncthreads();
        #pragma unroll
        for (int rr = 0; rr < 4; ++rr) {
            int u = rr * 256 + tid;
            int row = u >> 3, c8 = u & 7;
            size_t ga = (size_t)(r0 + row) * 1024 + kt * 64 + c8 * 8;
            size_t gb = (size_t)(c0 + row) * 1024 + kt * 64 + c8 * 8;
            __builtin_amdgcn_global_load_lds(&A[ga],  &As[u * 8], 16, 0, 0);
            __builtin_amdgcn_global_load_lds(&BT[gb], &Bs[u * 8], 16, 0, 0);
        }
        __syncthreads();

        #pragma unroll
        for (int ks = 0; ks < 2; ++ks) {
            int kb = (ks * 32 + l4 * 8) * 2;
            f16x8 af[4], bf[4];
            #pragma unroll
            for (int f = 0; f < 4; ++f) {
                int ar = wr * 64 + f * 16 + l15;
                int br = wc * 64 + f * 16 + l15;
                af[f] = *(const f16x8*)((char*)As + ar * 128 + kb);
                bf[f] = *(const f16x8*)((char*)Bs + br * 128 + kb);
            }
            #pragma unroll
            for (int i = 0; i < 4; ++i)
                #pragma unroll
                for (int j = 0; j < 4; ++j)
                    acc[i][j] = __builtin_amdgcn_mfma_f32_16x16x32_f16(
                        af[i], bf[j], acc[i][j], 0, 0, 0);
        }
    }

    #pragma unroll
    for (int i = 0; i < 4; ++i) {
        int grow0 = r0 + wr * 64 + i * 16 + l4 * 4;
        #pragma unroll
        for (int j = 0; j < 4; ++j) {
            int gcol = c0 + wc * 64 + j * 16 + l15;
            #pragma unroll
            for (int r = 0; r < 4; ++r)
                out[(size_t)(grow0 + r) * 1024 + gcol] = acc[i][j][r];
        }
    }
}

// ---------------------------------------------------------------------------
extern "C" void kernel_launch(void* const* d_in, const int* in_sizes, int n_in,
                              void* d_out, int out_size, void* d_ws, size_t ws_size,
                              hipStream_t stream) {
    const float* emb = (const float*)d_in[0];
    const float* Wq  = (const float*)d_in[1];
    const float* Wk  = (const float*)d_in[2];
    const float* Wv  = (const float*)d_in[3];
    const float* Wo  = (const float*)d_in[4];
    float* out = (float*)d_out;

    // ws: 52 MB with aliasing (lifetimes checked against stream order)
    _Float16* embH = (_Float16*)d_ws;          // 4M f16   [K2H aliases later]
    _Float16* embL = embH + 4194304;           // 4M       [K2L aliases later]
    _Float16* WTh  = embL + 4194304;           // 3M       [CC aliases later]
    _Float16* WTl  = WTh + 3145728;            // 2M
    _Float16* WoT  = WTl + 2097152;            // 1M
    _Float16* QbH  = WoT + 1048576;            // 4M
    _Float16* QbL  = QbH + 4194304;            // 4M
    _Float16* V2   = QbL + 4194304;            // 4M  -> total 26M f16 = 52 MB
    _Float16* K2H  = embH;                     // alias: emb dead after gemm_qkv
    _Float16* K2L  = embL;
    _Float16* CC   = WTh;                      // alias: WT dead after gemm_qkv
    // kkT hi/lo parked in d_out (16 MB), dead before gemm_out writes it
    _Float16* kkTH = (_Float16*)d_out;
    _Float16* kkTL = kkTH + 4194304;

    prep     <<<3072, 256, 0, stream>>>(emb, Wq, Wk, Wv, Wo,
                                        embH, embL, WTh, WTl, WoT);
    gemm_qkv <<<768, 256, 0, stream>>>(embH, embL, WTh, WTl,
                                       QbH, QbL, kkTH, kkTL, V2);
    trans_k  <<<dim3(16, 64, 2), 256, 0, stream>>>(kkTH, kkTL, K2H, K2L);
    attn     <<<1024, 256, 0, stream>>>(QbH, QbL, K2H, K2L, V2, CC);
    gemm_out <<<256, 256, 0, stream>>>(CC, WoT, out);
}

// Round 9
// 254.851 us; speedup vs baseline: 1.4670x; 1.4670x over previous
//
#include <hip/hip_runtime.h>
#include <math.h>

#define H 16
#define B 4
#define S 1024
#define E 1024
#define DK 64

typedef _Float16 f16x8 __attribute__((ext_vector_type(8)));
typedef _Float16 f16x4 __attribute__((ext_vector_type(4)));
typedef float    f32x4 __attribute__((ext_vector_type(4)));

// XOR-swizzle for [r][64 f16] tiles (128B row stride) — reg-staged LDS only.
__device__ __forceinline__ int swzb(int row, int colByte) {
    return row * 128 + (colByte ^ ((row & 7) << 4));
}

// ---------------------------------------------------------------------------
// prep: merged input conversion (one launch instead of two).
// bid < 2048:  emb f32 -> embH/embL (double-f16 split), 8 elems/thread.
// bid >= 2048: weight conversion (et = idx&15, cy = idx>>4):
//   cy<48: Wq/Wk/Wv [h][e][d] -> WTh [n][e] (+WTl n<2048), transposed+split.
//   cy>=48: Wo [k][n] -> WoT [n][k] f16.
// ---------------------------------------------------------------------------
__global__ __launch_bounds__(256) void prep(
    const float* __restrict__ emb,
    const float* __restrict__ Wq, const float* __restrict__ Wk,
    const float* __restrict__ Wv, const float* __restrict__ Wo,
    _Float16* __restrict__ embH, _Float16* __restrict__ embL,
    _Float16* __restrict__ WTh, _Float16* __restrict__ WTl,
    _Float16* __restrict__ WoT) {
    __shared__ _Float16 Th[64 * 64];
    __shared__ _Float16 Tl[64 * 64];
    int bid = blockIdx.x, tid = threadIdx.x;
    if (bid < 2048) {
        int i = (bid * 256 + tid) * 8;
        float4 a = *(const float4*)&emb[i];
        float4 bb = *(const float4*)&emb[i + 4];
        float x[8] = {a.x, a.y, a.z, a.w, bb.x, bb.y, bb.z, bb.w};
        f16x8 hv, lv;
        #pragma unroll
        for (int j = 0; j < 8; ++j) {
            _Float16 hh = (_Float16)x[j];
            hv[j] = hh;
            lv[j] = (_Float16)(x[j] - (float)hh);
        }
        *(f16x8*)&embH[i] = hv;
        *(f16x8*)&embL[i] = lv;
        return;
    }
    int idx = bid - 2048;
    int et = idx & 15, cy = idx >> 4;
    if (cy < 48) {
        const float* W = (cy < 16 ? Wq : cy < 32 ? Wk : Wv)
                         + (size_t)(cy & 15) * E * DK;
        #pragma unroll
        for (int rr = 0; rr < 4; ++rr) {
            int u = rr * 256 + tid;
            int ei = u >> 4, f4 = u & 15;
            float4 v = *(const float4*)&W[(size_t)(et * 64 + ei) * 64 + f4 * 4];
            float x[4] = {v.x, v.y, v.z, v.w};
            f16x4 h, l;
            #pragma unroll
            for (int j = 0; j < 4; ++j) {
                _Float16 hh = (_Float16)x[j];
                h[j] = hh;
                l[j] = (_Float16)(x[j] - (float)hh);
            }
            *(f16x4*)((char*)Th + swzb(ei, f4 * 8)) = h;
            *(f16x4*)((char*)Tl + swzb(ei, f4 * 8)) = l;
        }
        __syncthreads();
        #pragma unroll
        for (int rr = 0; rr < 2; ++rr) {
            int u = rr * 256 + tid;
            int d = u >> 3, e8 = u & 7;
            f16x8 oh, ol;
            #pragma unroll
            for (int j = 0; j < 8; ++j) {
                int ei = e8 * 8 + j;
                oh[j] = *(_Float16*)((char*)Th + swzb(ei, d * 2));
                ol[j] = *(_Float16*)((char*)Tl + swzb(ei, d * 2));
            }
            size_t o = (size_t)(cy * 64 + d) * 1024 + et * 64 + e8 * 8;
            *(f16x8*)&WTh[o] = oh;
            if (cy < 32) *(f16x8*)&WTl[o] = ol;
        }
    } else {
        int kt = et, nt = cy - 48;
        #pragma unroll
        for (int rr = 0; rr < 4; ++rr) {
            int u = rr * 256 + tid;
            int ki = u >> 4, f4 = u & 15;
            float4 v = *(const float4*)&Wo[(size_t)(kt * 64 + ki) * 1024 + nt * 64 + f4 * 4];
            f16x4 o = { (_Float16)v.x, (_Float16)v.y, (_Float16)v.z, (_Float16)v.w };
            *(f16x4*)((char*)Th + swzb(ki, f4 * 8)) = o;
        }
        __syncthreads();
        #pragma unroll
        for (int rr = 0; rr < 2; ++rr) {
            int u = rr * 256 + tid;
            int nl = u >> 3, k8 = u & 7;
            f16x8 o;
            #pragma unroll
            for (int j = 0; j < 8; ++j) {
                int ki = k8 * 8 + j;
                o[j] = *(_Float16*)((char*)Th + swzb(ki, nl * 2));
            }
            *(f16x8*)&WoT[(size_t)(nt * 64 + nl) * 1024 + kt * 64 + k8 * 8] = o;
        }
    }
}

// ---------------------------------------------------------------------------
// Fused QKV projection. grid 768 = 32 mt x 24 nt, XCD-bijective decode.
// nt<16: Q,K double-f16 (3-term MFMA), BK=32, linear LDS.
// nt>=16: V single-term, BK=64, linear LDS.
// ---------------------------------------------------------------------------
__global__ __launch_bounds__(256) void gemm_qkv(
    const _Float16* __restrict__ AH, const _Float16* __restrict__ AL,
    const _Float16* __restrict__ BTh, const _Float16* __restrict__ BTl,
    _Float16* __restrict__ QbH, _Float16* __restrict__ QbL,
    _Float16* __restrict__ kkTH, _Float16* __restrict__ kkTL,
    _Float16* __restrict__ V2) {
    __shared__ _Float16 SA[128 * 64];   // QK: H half [0,4096), L half [4096,8192)
    __shared__ _Float16 SB[128 * 64];
    int wg = ((int)blockIdx.x & 7) * 96 + ((int)blockIdx.x >> 3);
    int mt = wg / 24, nt = wg % 24;
    int r0 = mt * 128;
    int tid = threadIdx.x, lane = tid & 63, w = tid >> 6;
    int wr = w >> 1, wc = w & 1;
    int l15 = lane & 15, l4 = lane >> 4;

    f32x4 zero = {0.f, 0.f, 0.f, 0.f};
    f32x4 acc[4][4];
    #pragma unroll
    for (int i = 0; i < 4; ++i)
        #pragma unroll
        for (int j = 0; j < 4; ++j) acc[i][j] = zero;

    if (nt < 16) {
        // ---------------- Q,K path (double-f16, BK=32) ----------------
        int c0 = nt * 128;
        for (int kt = 0; kt < 32; ++kt) {
            __syncthreads();
            #pragma unroll
            for (int rr = 0; rr < 2; ++rr) {
                int u = rr * 256 + tid;
                int row = u >> 2, c8 = u & 3;
                size_t ga = (size_t)(r0 + row) * 1024 + kt * 32 + c8 * 8;
                size_t gb = (size_t)(c0 + row) * 1024 + kt * 32 + c8 * 8;
                __builtin_amdgcn_global_load_lds(&AH[ga],  &SA[u * 8], 16, 0, 0);
                __builtin_amdgcn_global_load_lds(&AL[ga],  &SA[4096 + u * 8], 16, 0, 0);
                __builtin_amdgcn_global_load_lds(&BTh[gb], &SB[u * 8], 16, 0, 0);
                __builtin_amdgcn_global_load_lds(&BTl[gb], &SB[4096 + u * 8], 16, 0, 0);
            }
            __syncthreads();

            int kb = l4 * 16;
            f16x8 afH[4], afL[4], bfH[4], bfL[4];
            #pragma unroll
            for (int f = 0; f < 4; ++f) {
                int ar = wr * 64 + f * 16 + l15;
                int br = wc * 64 + f * 16 + l15;
                afH[f] = *(const f16x8*)((char*)SA + ar * 64 + kb);
                afL[f] = *(const f16x8*)((char*)SA + 8192 + ar * 64 + kb);
                bfH[f] = *(const f16x8*)((char*)SB + br * 64 + kb);
                bfL[f] = *(const f16x8*)((char*)SB + 8192 + br * 64 + kb);
            }
            #pragma unroll
            for (int i = 0; i < 4; ++i)
                #pragma unroll
                for (int j = 0; j < 4; ++j) {
                    acc[i][j] = __builtin_amdgcn_mfma_f32_16x16x32_f16(
                        afH[i], bfH[j], acc[i][j], 0, 0, 0);
                    acc[i][j] = __builtin_amdgcn_mfma_f32_16x16x32_f16(
                        afH[i], bfL[j], acc[i][j], 0, 0, 0);
                    acc[i][j] = __builtin_amdgcn_mfma_f32_16x16x32_f16(
                        afL[i], bfH[j], acc[i][j], 0, 0, 0);
                }
        }

        #pragma unroll
        for (int i = 0; i < 4; ++i) {
            int grow0 = r0 + wr * 64 + i * 16 + l4 * 4;
            #pragma unroll
            for (int j = 0; j < 4; ++j) {
                int gcol = c0 + wc * 64 + j * 16 + l15;
                if (gcol < 1024) {                       // ---- Q (split) ----
                    int hh = gcol >> 6, dk = gcol & 63;
                    #pragma unroll
                    for (int r = 0; r < 4; ++r) {
                        int grow = grow0 + r;
                        int bb = grow >> 10, s = grow & 1023;
                        float v = acc[i][j][r];
                        _Float16 hq = (_Float16)v;
                        size_t o = (((size_t)hh * 4 + bb) * 1024 + s) * 64 + dk;
                        QbH[o] = hq;
                        QbL[o] = (_Float16)(v - (float)hq);
                    }
                } else {                                 // ---- K (split, reshaped) ----
                    int hh = (gcol >> 6) & 15, dk = gcol & 63;
                    #pragma unroll
                    for (int r = 0; r < 4; ++r) {
                        int grow = grow0 + r;
                        int bb = grow >> 10, s = grow & 1023;
                        float v = acc[i][j][r];
                        _Float16 hq = (_Float16)v;
                        size_t o = (((size_t)hh * 4 + bb) * 64 + (s >> 4)) * 1024
                                   + (s & 15) * 64 + dk;
                        kkTH[o] = hq;
                        kkTL[o] = (_Float16)(v - (float)hq);
                    }
                }
            }
        }
    } else {
        // ---------------- V path (single f16, BK=64) ----------------
        int c0 = (nt - 16) * 128;            // V2 columns; weights at 2048+c0
        for (int kt = 0; kt < 16; ++kt) {
            __syncthreads();
            #pragma unroll
            for (int rr = 0; rr < 4; ++rr) {
                int u = rr * 256 + tid;
                int row = u >> 3, c8 = u & 7;
                size_t ga = (size_t)(r0 + row) * 1024 + kt * 64 + c8 * 8;
                size_t gb = (size_t)(2048 + c0 + row) * 1024 + kt * 64 + c8 * 8;
                __builtin_amdgcn_global_load_lds(&AH[ga],  &SA[u * 8], 16, 0, 0);
                __builtin_amdgcn_global_load_lds(&BTh[gb], &SB[u * 8], 16, 0, 0);
            }
            __syncthreads();

            #pragma unroll
            for (int ks = 0; ks < 2; ++ks) {
                int kb = (ks * 32 + l4 * 8) * 2;
                f16x8 af[4], bf[4];
                #pragma unroll
                for (int f = 0; f < 4; ++f) {
                    int ar = wr * 64 + f * 16 + l15;
                    int br = wc * 64 + f * 16 + l15;
                    af[f] = *(const f16x8*)((char*)SA + ar * 128 + kb);
                    bf[f] = *(const f16x8*)((char*)SB + br * 128 + kb);
                }
                #pragma unroll
                for (int i = 0; i < 4; ++i)
                    #pragma unroll
                    for (int j = 0; j < 4; ++j)
                        acc[i][j] = __builtin_amdgcn_mfma_f32_16x16x32_f16(
                            af[i], bf[j], acc[i][j], 0, 0, 0);
            }
        }

        #pragma unroll
        for (int i = 0; i < 4; ++i) {
            int grow0 = r0 + wr * 64 + i * 16 + l4 * 4;
            int bb = grow0 >> 10, s = grow0 & 1023;
            #pragma unroll
            for (int j = 0; j < 4; ++j) {
                int gcol = c0 + wc * 64 + j * 16 + l15;
                int hh = gcol >> 6, dv = gcol & 63;
                f16x4 o = { (_Float16)acc[i][j][0], (_Float16)acc[i][j][1],
                            (_Float16)acc[i][j][2], (_Float16)acc[i][j][3] };
                *(f16x4*)&V2[(((size_t)hh * 4 + bb) * 64 + dv) * 1024 + s] = o;
            }
        }
    }
}

// ---------------------------------------------------------------------------
// kkT [hb][64 d][1024 t] -> K2 [hb][1024 t][64 d], modes: 0=hi, 1=lo.
// ---------------------------------------------------------------------------
__global__ __launch_bounds__(256) void trans_k(const _Float16* __restrict__ kkTH,
                                               const _Float16* __restrict__ kkTL,
                                               _Float16* __restrict__ K2H,
                                               _Float16* __restrict__ K2L) {
    int tt = blockIdx.x;
    size_t hb = blockIdx.y;
    int mode = blockIdx.z;
    const _Float16* src = mode ? kkTL : kkTH;
    _Float16* dst = mode ? K2L : K2H;
    __shared__ _Float16 T[64 * 64];
    int tid = threadIdx.x;
    #pragma unroll
    for (int rr = 0; rr < 2; ++rr) {
        int u = rr * 256 + tid;
        int d = u >> 3, c8 = u & 7;
        f16x8 v = *(const f16x8*)&src[(hb * 64 + d) * 1024 + tt * 64 + c8 * 8];
        *(f16x8*)((char*)T + swzb(d, c8 * 16)) = v;
    }
    __syncthreads();
    #pragma unroll
    for (int rr = 0; rr < 2; ++rr) {
        int u = rr * 256 + tid;
        int ti = u >> 3, d8 = u & 7;
        f16x8 o;
        #pragma unroll
        for (int j = 0; j < 8; ++j)
            o[j] = *(_Float16*)((char*)T + swzb(d8 * 8 + j, ti * 2));
        *(f16x8*)&dst[(hb * 1024 + tt * 64 + ti) * 64 + d8 * 8] = o;
    }
}

// ---------------------------------------------------------------------------
// Flash attention, double-f16 QK^T (3 terms). STAGED K/V (r7 structure —
// r8 proved staging-free is latency-bound: MfmaUtil 3.9%, 178us). Q frags
// direct from global (r8-verified, saves 16KB LDS -> 32KB total, 5 blk/CU).
// T14 reg prefetch, LPT order, setprio. Output -> scrambled concat CC, f16.
// ---------------------------------------------------------------------------
__global__ __launch_bounds__(256) void attn(
    const _Float16* __restrict__ QbH, const _Float16* __restrict__ QbL,
    const _Float16* __restrict__ K2H, const _Float16* __restrict__ K2L,
    const _Float16* __restrict__ V2, _Float16* __restrict__ CC) {
    int qt = 15 - (int)blockIdx.x;       // LPT: long blocks dispatch first
    int b = blockIdx.y, h = blockIdx.z;
    size_t hb = (size_t)h * 4 + b;
    __shared__ _Float16 KsH[64 * 64], KsL[64 * 64];
    __shared__ _Float16 Vs[64 * 64], Ps[64 * 64];
    int tid = threadIdx.x, lane = tid & 63, w = tid >> 6;
    int l15 = lane & 15, l4 = lane >> 4;
    int s0 = qt * 64;
    int srow = w * 16 + l15;
    int sg = s0 + srow;

    // Q frags: direct global load (r8-verified path)
    f16x8 qfH[2], qfL[2];
    #pragma unroll
    for (int ks = 0; ks < 2; ++ks) {
        size_t qa = (hb * 1024 + s0 + srow) * 64 + ks * 32 + l4 * 8;
        qfH[ks] = *(const f16x8*)&QbH[qa];
        qfL[ks] = *(const f16x8*)&QbL[qa];
    }
    // prologue: load tile 0 into regs
    f16x8 rkH[2], rkL[2], rv[2];
    #pragma unroll
    for (int rr = 0; rr < 2; ++rr) {
        int u = rr * 256 + tid, row = u >> 3, c8 = u & 7;
        size_t ki = (hb * 1024 + row) * 64 + c8 * 8;
        rkH[rr] = *(const f16x8*)&K2H[ki];
        rkL[rr] = *(const f16x8*)&K2L[ki];
        rv[rr]  = *(const f16x8*)&V2[(hb * 64 + row) * 1024 + c8 * 8];
    }

    float m = -__builtin_inff(), lsum = 0.f;
    f32x4 zero = {0.f, 0.f, 0.f, 0.f};
    f32x4 acc2[4] = {zero, zero, zero, zero};
    int ntile = qt + 1;

    for (int tt = 0; tt < ntile; ++tt) {
        int t0 = tt * 64;
        __syncthreads();                 // prev tile's LDS reads done
        #pragma unroll
        for (int rr = 0; rr < 2; ++rr) { // write current tile from regs
            int u = rr * 256 + tid, row = u >> 3, c8 = u & 7;
            int off = swzb(row, c8 * 16);
            *(f16x8*)((char*)KsH + off) = rkH[rr];
            *(f16x8*)((char*)KsL + off) = rkL[rr];
            *(f16x8*)((char*)Vs + off)  = rv[rr];
        }
        if (tt + 1 < ntile) {            // issue next-tile loads (in flight
            int t0n = t0 + 64;           // during this tile's compute)
            #pragma unroll
            for (int rr = 0; rr < 2; ++rr) {
                int u = rr * 256 + tid, row = u >> 3, c8 = u & 7;
                size_t ki = (hb * 1024 + t0n + row) * 64 + c8 * 8;
                rkH[rr] = *(const f16x8*)&K2H[ki];
                rkL[rr] = *(const f16x8*)&K2L[ki];
                rv[rr]  = *(const f16x8*)&V2[(hb * 64 + row) * 1024 + t0n + c8 * 8];
            }
        }
        __syncthreads();

        f32x4 z[4] = {zero, zero, zero, zero};
        __builtin_amdgcn_s_setprio(1);
        #pragma unroll
        for (int ks = 0; ks < 2; ++ks) {
            int kb = (ks * 32 + l4 * 8) * 2;
            #pragma unroll
            for (int f = 0; f < 4; ++f) {
                int trow = f * 16 + l15;
                f16x8 akH = *(const f16x8*)((char*)KsH + swzb(trow, kb));
                f16x8 akL = *(const f16x8*)((char*)KsL + swzb(trow, kb));
                z[f] = __builtin_amdgcn_mfma_f32_16x16x32_f16(akH, qfH[ks], z[f], 0, 0, 0);
                z[f] = __builtin_amdgcn_mfma_f32_16x16x32_f16(akH, qfL[ks], z[f], 0, 0, 0);
                z[f] = __builtin_amdgcn_mfma_f32_16x16x32_f16(akL, qfH[ks], z[f], 0, 0, 0);
            }
        }
        __builtin_amdgcn_s_setprio(0);
        // scale + causal mask + lane-local row max
        float mt = -__builtin_inff();
        #pragma unroll
        for (int f = 0; f < 4; ++f)
            #pragma unroll
            for (int r = 0; r < 4; ++r) {
                int tg = t0 + f * 16 + l4 * 4 + r;
                float val = z[f][r] * 0.125f;
                val = (tg > sg) ? -__builtin_inff() : val;
                z[f][r] = val;
                mt = fmaxf(mt, val);
            }
        mt = fmaxf(mt, __shfl_xor(mt, 16));
        mt = fmaxf(mt, __shfl_xor(mt, 32));
        float mn = fmaxf(m, mt);
        float corr = __expf(m - mn);
        float ps = 0.f;
        #pragma unroll
        for (int f = 0; f < 4; ++f)
            #pragma unroll
            for (int r = 0; r < 4; ++r) {
                float p = __expf(z[f][r] - mn);
                z[f][r] = p;
                ps += p;
            }
        ps += __shfl_xor(ps, 16);
        ps += __shfl_xor(ps, 32);
        lsum = lsum * corr + ps;
        m = mn;
        #pragma unroll
        for (int f = 0; f < 4; ++f) acc2[f] *= corr;

        // P^T -> Ps (wave-private rows, no barrier needed)
        #pragma unroll
        for (int f = 0; f < 4; ++f) {
            f16x4 pk = { (_Float16)z[f][0], (_Float16)z[f][1],
                         (_Float16)z[f][2], (_Float16)z[f][3] };
            *(f16x4*)((char*)Ps + swzb(srow, (f * 16 + l4 * 4) * 2)) = pk;
        }
        __builtin_amdgcn_s_setprio(1);
        #pragma unroll
        for (int ks = 0; ks < 2; ++ks) {
            int kb = (ks * 32 + l4 * 8) * 2;
            f16x8 bp = *(const f16x8*)((char*)Ps + swzb(srow, kb));
            #pragma unroll
            for (int f = 0; f < 4; ++f) {
                int dvrow = f * 16 + l15;
                f16x8 av = *(const f16x8*)((char*)Vs + swzb(dvrow, kb));
                acc2[f] = __builtin_amdgcn_mfma_f32_16x16x32_f16(av, bp, acc2[f], 0, 0, 0);
            }
        }
        __builtin_amdgcn_s_setprio(0);
    }

    float inv = 1.f / lsum;
    int sp = s0 + srow;
    int bprow = h >> 2;
    int spp = (h & 3) * 256 + b * 64 + (sp >> 4);
    int cb = (sp & 15) * 64;
    #pragma unroll
    for (int f = 0; f < 4; ++f) {
        int dv = f * 16 + l4 * 4;
        f16x4 o = { (_Float16)(acc2[f][0] * inv), (_Float16)(acc2[f][1] * inv),
                    (_Float16)(acc2[f][2] * inv), (_Float16)(acc2[f][3] * inv) };
        *(f16x4*)&CC[((size_t)bprow * 1024 + spp) * 1024 + cb + dv] = o;
    }
}

// ---------------------------------------------------------------------------
// Output projection: CC[4096][1024] @ WoT[1024][1024]^T -> out f32.
// m97 structure: 128x128 tile, BK=64, gload_lds, linear LDS.
// ---------------------------------------------------------------------------
__global__ __launch_bounds__(256) void gemm_out(
    const _Float16* __restrict__ A, const _Float16* __restrict__ BT,
    float* __restrict__ out) {
    __shared__ _Float16 As[128 * 64];
    __shared__ _Float16 Bs[128 * 64];
    int wg = ((int)blockIdx.x & 7) * 32 + ((int)blockIdx.x >> 3);
    int mt = wg >> 3, nt = wg & 7;
    int r0 = mt * 128, c0 = nt * 128;
    int tid = threadIdx.x, lane = tid & 63, w = tid >> 6;
    int wr = w >> 1, wc = w & 1;
    int l15 = lane & 15, l4 = lane >> 4;

    f32x4 zero = {0.f, 0.f, 0.f, 0.f};
    f32x4 acc[4][4];
    #pragma unroll
    for (int i = 0; i < 4; ++i)
        #pragma unroll
        for (int j = 0; j < 4; ++j) acc[i][j] = zero;

    for (int kt = 0; kt < 16; ++kt) {
        __syncthreads();
        #pragma unroll
        for (int rr = 0; rr < 4; ++rr) {
            int u = rr * 256 + tid;
            int row = u >> 3, c8 = u & 7;
            size_t ga = (size_t)(r0 + row) * 1024 + kt * 64 + c8 * 8;
            size_t gb = (size_t)(c0 + row) * 1024 + kt * 64 + c8 * 8;
            __builtin_amdgcn_global_load_lds(&A[ga],  &As[u * 8], 16, 0, 0);
            __builtin_amdgcn_global_load_lds(&BT[gb], &Bs[u * 8], 16, 0, 0);
        }
        __syncthreads();

        #pragma unroll
        for (int ks = 0; ks < 2; ++ks) {
            int kb = (ks * 32 + l4 * 8) * 2;
            f16x8 af[4], bf[4];
            #pragma unroll
            for (int f = 0; f < 4; ++f) {
                int ar = wr * 64 + f * 16 + l15;
                int br = wc * 64 + f * 16 + l15;
                af[f] = *(const f16x8*)((char*)As + ar * 128 + kb);
                bf[f] = *(const f16x8*)((char*)Bs + br * 128 + kb);
            }
            #pragma unroll
            for (int i = 0; i < 4; ++i)
                #pragma unroll
                for (int j = 0; j < 4; ++j)
                    acc[i][j] = __builtin_amdgcn_mfma_f32_16x16x32_f16(
                        af[i], bf[j], acc[i][j], 0, 0, 0);
        }
    }

    #pragma unroll
    for (int i = 0; i < 4; ++i) {
        int grow0 = r0 + wr * 64 + i * 16 + l4 * 4;
        #pragma unroll
        for (int j = 0; j < 4; ++j) {
            int gcol = c0 + wc * 64 + j * 16 + l15;
            #pragma unroll
            for (int r = 0; r < 4; ++r)
                out[(size_t)(grow0 + r) * 1024 + gcol] = acc[i][j][r];
        }
    }
}

// ---------------------------------------------------------------------------
extern "C" void kernel_launch(void* const* d_in, const int* in_sizes, int n_in,
                              void* d_out, int out_size, void* d_ws, size_t ws_size,
                              hipStream_t stream) {
    const float* emb = (const float*)d_in[0];
    const float* Wq  = (const float*)d_in[1];
    const float* Wk  = (const float*)d_in[2];
    const float* Wv  = (const float*)d_in[3];
    const float* Wo  = (const float*)d_in[4];
    float* out = (float*)d_out;

    // ws: 52 MB with aliasing (lifetimes checked against stream order)
    _Float16* embH = (_Float16*)d_ws;          // 4M f16   [K2H aliases later]
    _Float16* embL = embH + 4194304;           // 4M       [K2L aliases later]
    _Float16* WTh  = embL + 4194304;           // 3M       [CC aliases later]
    _Float16* WTl  = WTh + 3145728;            // 2M
    _Float16* WoT  = WTl + 2097152;            // 1M
    _Float16* QbH  = WoT + 1048576;            // 4M
    _Float16* QbL  = QbH + 4194304;            // 4M
    _Float16* V2   = QbL + 4194304;            // 4M  -> total 26M f16 = 52 MB
    _Float16* K2H  = embH;                     // alias: emb dead after gemm_qkv
    _Float16* K2L  = embL;
    _Float16* CC   = WTh;                      // alias: WT dead after gemm_qkv
    // kkT hi/lo parked in d_out (16 MB), dead before gemm_out writes it
    _Float16* kkTH = (_Float16*)d_out;
    _Float16* kkTL = kkTH + 4194304;

    prep     <<<3072, 256, 0, stream>>>(emb, Wq, Wk, Wv, Wo,
                                        embH, embL, WTh, WTl, WoT);
    gemm_qkv <<<768, 256, 0, stream>>>(embH, embL, WTh, WTl,
                                       QbH, QbL, kkTH, kkTL, V2);
    trans_k  <<<dim3(16, 64, 2), 256, 0, stream>>>(kkTH, kkTL, K2H, K2L);
    attn     <<<dim3(16, 4, 16), 256, 0, stream>>>(QbH, QbL, K2H, K2L, V2, CC);
    gemm_out <<<256, 256, 0, stream>>>(CC, WoT, out);
}

// Round 10
// 245.923 us; speedup vs baseline: 1.5203x; 1.0363x over previous
//
#include <hip/hip_runtime.h>
#include <math.h>

#define H 16
#define B 4
#define S 1024
#define E 1024
#define DK 64

typedef _Float16 f16x8 __attribute__((ext_vector_type(8)));
typedef _Float16 f16x4 __attribute__((ext_vector_type(4)));
typedef float    f32x4 __attribute__((ext_vector_type(4)));

// XOR-swizzle for [r][64 f16] tiles (128B row stride) — reg-staged LDS only.
__device__ __forceinline__ int swzb(int row, int colByte) {
    return row * 128 + (colByte ^ ((row & 7) << 4));
}

// ---------------------------------------------------------------------------
// prep: merged input conversion.
// bid < 2048:  emb f32 -> embH/embL (double-f16 split), 8 elems/thread.
// bid >= 2048: weight conversion (et = idx&15, cy = idx>>4):
//   cy<48: Wq/Wk/Wv [h][e][d] -> WTh [n][e] (+WTl n<2048), transposed+split.
//   cy>=48: Wo [k][n] -> WoT [n][k] f16.
// ---------------------------------------------------------------------------
__global__ __launch_bounds__(256) void prep(
    const float* __restrict__ emb,
    const float* __restrict__ Wq, const float* __restrict__ Wk,
    const float* __restrict__ Wv, const float* __restrict__ Wo,
    _Float16* __restrict__ embH, _Float16* __restrict__ embL,
    _Float16* __restrict__ WTh, _Float16* __restrict__ WTl,
    _Float16* __restrict__ WoT) {
    __shared__ _Float16 Th[64 * 64];
    __shared__ _Float16 Tl[64 * 64];
    int bid = blockIdx.x, tid = threadIdx.x;
    if (bid < 2048) {
        int i = (bid * 256 + tid) * 8;
        float4 a = *(const float4*)&emb[i];
        float4 bb = *(const float4*)&emb[i + 4];
        float x[8] = {a.x, a.y, a.z, a.w, bb.x, bb.y, bb.z, bb.w};
        f16x8 hv, lv;
        #pragma unroll
        for (int j = 0; j < 8; ++j) {
            _Float16 hh = (_Float16)x[j];
            hv[j] = hh;
            lv[j] = (_Float16)(x[j] - (float)hh);
        }
        *(f16x8*)&embH[i] = hv;
        *(f16x8*)&embL[i] = lv;
        return;
    }
    int idx = bid - 2048;
    int et = idx & 15, cy = idx >> 4;
    if (cy < 48) {
        const float* W = (cy < 16 ? Wq : cy < 32 ? Wk : Wv)
                         + (size_t)(cy & 15) * E * DK;
        #pragma unroll
        for (int rr = 0; rr < 4; ++rr) {
            int u = rr * 256 + tid;
            int ei = u >> 4, f4 = u & 15;
            float4 v = *(const float4*)&W[(size_t)(et * 64 + ei) * 64 + f4 * 4];
            float x[4] = {v.x, v.y, v.z, v.w};
            f16x4 h, l;
            #pragma unroll
            for (int j = 0; j < 4; ++j) {
                _Float16 hh = (_Float16)x[j];
                h[j] = hh;
                l[j] = (_Float16)(x[j] - (float)hh);
            }
            *(f16x4*)((char*)Th + swzb(ei, f4 * 8)) = h;
            *(f16x4*)((char*)Tl + swzb(ei, f4 * 8)) = l;
        }
        __syncthreads();
        #pragma unroll
        for (int rr = 0; rr < 2; ++rr) {
            int u = rr * 256 + tid;
            int d = u >> 3, e8 = u & 7;
            f16x8 oh, ol;
            #pragma unroll
            for (int j = 0; j < 8; ++j) {
                int ei = e8 * 8 + j;
                oh[j] = *(_Float16*)((char*)Th + swzb(ei, d * 2));
                ol[j] = *(_Float16*)((char*)Tl + swzb(ei, d * 2));
            }
            size_t o = (size_t)(cy * 64 + d) * 1024 + et * 64 + e8 * 8;
            *(f16x8*)&WTh[o] = oh;
            if (cy < 32) *(f16x8*)&WTl[o] = ol;
        }
    } else {
        int kt = et, nt = cy - 48;
        #pragma unroll
        for (int rr = 0; rr < 4; ++rr) {
            int u = rr * 256 + tid;
            int ki = u >> 4, f4 = u & 15;
            float4 v = *(const float4*)&Wo[(size_t)(kt * 64 + ki) * 1024 + nt * 64 + f4 * 4];
            f16x4 o = { (_Float16)v.x, (_Float16)v.y, (_Float16)v.z, (_Float16)v.w };
            *(f16x4*)((char*)Th + swzb(ki, f4 * 8)) = o;
        }
        __syncthreads();
        #pragma unroll
        for (int rr = 0; rr < 2; ++rr) {
            int u = rr * 256 + tid;
            int nl = u >> 3, k8 = u & 7;
            f16x8 o;
            #pragma unroll
            for (int j = 0; j < 8; ++j) {
                int ki = k8 * 8 + j;
                o[j] = *(_Float16*)((char*)Th + swzb(ki, nl * 2));
            }
            *(f16x8*)&WoT[(size_t)(nt * 64 + nl) * 1024 + kt * 64 + k8 * 8] = o;
        }
    }
}

// ---------------------------------------------------------------------------
// Q,K projection GEMM (double-f16, 3-term MFMA). m97 structure:
// 128x128 tile, BK=32, linear LDS, global_load_lds(16B), 2-barrier loop.
// grid 512 = 32 mt x 16 nt. [r5/r7-proven: 61-63 us, MfmaUtil ~35%]
// ---------------------------------------------------------------------------
__global__ __launch_bounds__(256) void gemm_qk(
    const _Float16* __restrict__ AH, const _Float16* __restrict__ AL,
    const _Float16* __restrict__ BTh, const _Float16* __restrict__ BTl,
    _Float16* __restrict__ QbH, _Float16* __restrict__ QbL,
    _Float16* __restrict__ kkTH, _Float16* __restrict__ kkTL) {
    __shared__ _Float16 AsH[128 * 32], AsL[128 * 32];
    __shared__ _Float16 BsH[128 * 32], BsL[128 * 32];
    int wg = ((int)blockIdx.x & 7) * 64 + ((int)blockIdx.x >> 3);
    int mt = wg >> 4, nt = wg & 15;
    int r0 = mt * 128, c0 = nt * 128;
    int tid = threadIdx.x, lane = tid & 63, w = tid >> 6;
    int wr = w >> 1, wc = w & 1;
    int l15 = lane & 15, l4 = lane >> 4;

    f32x4 zero = {0.f, 0.f, 0.f, 0.f};
    f32x4 acc[4][4];
    #pragma unroll
    for (int i = 0; i < 4; ++i)
        #pragma unroll
        for (int j = 0; j < 4; ++j) acc[i][j] = zero;

    for (int kt = 0; kt < 32; ++kt) {
        __syncthreads();
        #pragma unroll
        for (int rr = 0; rr < 2; ++rr) {
            int u = rr * 256 + tid;
            int row = u >> 2, c8 = u & 3;
            size_t ga = (size_t)(r0 + row) * 1024 + kt * 32 + c8 * 8;
            size_t gb = (size_t)(c0 + row) * 1024 + kt * 32 + c8 * 8;
            __builtin_amdgcn_global_load_lds(&AH[ga],  &AsH[u * 8], 16, 0, 0);
            __builtin_amdgcn_global_load_lds(&AL[ga],  &AsL[u * 8], 16, 0, 0);
            __builtin_amdgcn_global_load_lds(&BTh[gb], &BsH[u * 8], 16, 0, 0);
            __builtin_amdgcn_global_load_lds(&BTl[gb], &BsL[u * 8], 16, 0, 0);
        }
        __syncthreads();

        int kb = l4 * 16;
        f16x8 afH[4], afL[4], bfH[4], bfL[4];
        #pragma unroll
        for (int f = 0; f < 4; ++f) {
            int ar = wr * 64 + f * 16 + l15;
            int br = wc * 64 + f * 16 + l15;
            afH[f] = *(const f16x8*)((char*)AsH + ar * 64 + kb);
            afL[f] = *(const f16x8*)((char*)AsL + ar * 64 + kb);
            bfH[f] = *(const f16x8*)((char*)BsH + br * 64 + kb);
            bfL[f] = *(const f16x8*)((char*)BsL + br * 64 + kb);
        }
        #pragma unroll
        for (int i = 0; i < 4; ++i)
            #pragma unroll
            for (int j = 0; j < 4; ++j) {
                acc[i][j] = __builtin_amdgcn_mfma_f32_16x16x32_f16(
                    afH[i], bfH[j], acc[i][j], 0, 0, 0);
                acc[i][j] = __builtin_amdgcn_mfma_f32_16x16x32_f16(
                    afH[i], bfL[j], acc[i][j], 0, 0, 0);
                acc[i][j] = __builtin_amdgcn_mfma_f32_16x16x32_f16(
                    afL[i], bfH[j], acc[i][j], 0, 0, 0);
            }
    }

    #pragma unroll
    for (int i = 0; i < 4; ++i) {
        int grow0 = r0 + wr * 64 + i * 16 + l4 * 4;
        #pragma unroll
        for (int j = 0; j < 4; ++j) {
            int gcol = c0 + wc * 64 + j * 16 + l15;
            if (gcol < 1024) {                       // ---- Q (split) ----
                int hh = gcol >> 6, dk = gcol & 63;
                #pragma unroll
                for (int r = 0; r < 4; ++r) {
                    int grow = grow0 + r;
                    int bb = grow >> 10, s = grow & 1023;
                    float v = acc[i][j][r];
                    _Float16 hq = (_Float16)v;
                    size_t o = (((size_t)hh * 4 + bb) * 1024 + s) * 64 + dk;
                    QbH[o] = hq;
                    QbL[o] = (_Float16)(v - (float)hq);
                }
            } else {                                 // ---- K (split, reshaped) ----
                int hh = (gcol >> 6) & 15, dk = gcol & 63;
                #pragma unroll
                for (int r = 0; r < 4; ++r) {
                    int grow = grow0 + r;
                    int bb = grow >> 10, s = grow & 1023;
                    float v = acc[i][j][r];
                    _Float16 hq = (_Float16)v;
                    size_t o = (((size_t)hh * 4 + bb) * 64 + (s >> 4)) * 1024
                               + (s & 15) * 64 + dk;
                    kkTH[o] = hq;
                    kkTL[o] = (_Float16)(v - (float)hq);
                }
            }
        }
    }
}

// ---------------------------------------------------------------------------
// V projection GEMM (single f16). gemm_out-clone structure: 128x128, BK=64,
// gload_lds, linear LDS. grid 256 = 32 mt x 8 nt. Writes V2 [hb][dv][t].
// ---------------------------------------------------------------------------
__global__ __launch_bounds__(256) void gemm_v(
    const _Float16* __restrict__ AH, const _Float16* __restrict__ BTh,
    _Float16* __restrict__ V2) {
    __shared__ _Float16 As[128 * 64];
    __shared__ _Float16 Bs[128 * 64];
    int wg = ((int)blockIdx.x & 7) * 32 + ((int)blockIdx.x >> 3);
    int mt = wg >> 3, nt = wg & 7;
    int r0 = mt * 128, c0 = nt * 128;     // V-weight rows live at 2048 + c0
    int tid = threadIdx.x, lane = tid & 63, w = tid >> 6;
    int wr = w >> 1, wc = w & 1;
    int l15 = lane & 15, l4 = lane >> 4;

    f32x4 zero = {0.f, 0.f, 0.f, 0.f};
    f32x4 acc[4][4];
    #pragma unroll
    for (int i = 0; i < 4; ++i)
        #pragma unroll
        for (int j = 0; j < 4; ++j) acc[i][j] = zero;

    for (int kt = 0; kt < 16; ++kt) {
        __syncthreads();
        #pragma unroll
        for (int rr = 0; rr < 4; ++rr) {
            int u = rr * 256 + tid;
            int row = u >> 3, c8 = u & 7;
            size_t ga = (size_t)(r0 + row) * 1024 + kt * 64 + c8 * 8;
            size_t gb = (size_t)(2048 + c0 + row) * 1024 + kt * 64 + c8 * 8;
            __builtin_amdgcn_global_load_lds(&AH[ga],  &As[u * 8], 16, 0, 0);
            __builtin_amdgcn_global_load_lds(&BTh[gb], &Bs[u * 8], 16, 0, 0);
        }
        __syncthreads();

        #pragma unroll
        for (int ks = 0; ks < 2; ++ks) {
            int kb = (ks * 32 + l4 * 8) * 2;
            f16x8 af[4], bf[4];
            #pragma unroll
            for (int f = 0; f < 4; ++f) {
                int ar = wr * 64 + f * 16 + l15;
                int br = wc * 64 + f * 16 + l15;
                af[f] = *(const f16x8*)((char*)As + ar * 128 + kb);
                bf[f] = *(const f16x8*)((char*)Bs + br * 128 + kb);
            }
            #pragma unroll
            for (int i = 0; i < 4; ++i)
                #pragma unroll
                for (int j = 0; j < 4; ++j)
                    acc[i][j] = __builtin_amdgcn_mfma_f32_16x16x32_f16(
                        af[i], bf[j], acc[i][j], 0, 0, 0);
        }
    }

    #pragma unroll
    for (int i = 0; i < 4; ++i) {
        int grow0 = r0 + wr * 64 + i * 16 + l4 * 4;
        int bb = grow0 >> 10, s = grow0 & 1023;
        #pragma unroll
        for (int j = 0; j < 4; ++j) {
            int gcol = c0 + wc * 64 + j * 16 + l15;     // [0,1024)
            int hh = gcol >> 6, dv = gcol & 63;
            f16x4 o = { (_Float16)acc[i][j][0], (_Float16)acc[i][j][1],
                        (_Float16)acc[i][j][2], (_Float16)acc[i][j][3] };
            *(f16x4*)&V2[(((size_t)hh * 4 + bb) * 64 + dv) * 1024 + s] = o;
        }
    }
}

// ---------------------------------------------------------------------------
// kkT [hb][64 d][1024 t] -> K2 [hb][1024 t][64 d], modes: 0=hi, 1=lo.
// ---------------------------------------------------------------------------
__global__ __launch_bounds__(256) void trans_k(const _Float16* __restrict__ kkTH,
                                               const _Float16* __restrict__ kkTL,
                                               _Float16* __restrict__ K2H,
                                               _Float16* __restrict__ K2L) {
    int tt = blockIdx.x;
    size_t hb = blockIdx.y;
    int mode = blockIdx.z;
    const _Float16* src = mode ? kkTL : kkTH;
    _Float16* dst = mode ? K2L : K2H;
    __shared__ _Float16 T[64 * 64];
    int tid = threadIdx.x;
    #pragma unroll
    for (int rr = 0; rr < 2; ++rr) {
        int u = rr * 256 + tid;
        int d = u >> 3, c8 = u & 7;
        f16x8 v = *(const f16x8*)&src[(hb * 64 + d) * 1024 + tt * 64 + c8 * 8];
        *(f16x8*)((char*)T + swzb(d, c8 * 16)) = v;
    }
    __syncthreads();
    #pragma unroll
    for (int rr = 0; rr < 2; ++rr) {
        int u = rr * 256 + tid;
        int ti = u >> 3, d8 = u & 7;
        f16x8 o;
        #pragma unroll
        for (int j = 0; j < 8; ++j)
            o[j] = *(_Float16*)((char*)T + swzb(d8 * 8 + j, ti * 2));
        *(f16x8*)&dst[(hb * 1024 + tt * 64 + ti) * 64 + d8 * 8] = o;
    }
}

// ---------------------------------------------------------------------------
// Flash attention, double-f16 QK^T (3 terms). STAGED K/V (r8 proved
// staging-free is latency-bound). Q frags direct from global (saves 16KB
// LDS -> 32KB, 5 blk/CU). T14 reg prefetch, LPT, setprio.
// ---------------------------------------------------------------------------
__global__ __launch_bounds__(256) void attn(
    const _Float16* __restrict__ QbH, const _Float16* __restrict__ QbL,
    const _Float16* __restrict__ K2H, const _Float16* __restrict__ K2L,
    const _Float16* __restrict__ V2, _Float16* __restrict__ CC) {
    int qt = 15 - (int)blockIdx.x;       // LPT: long blocks dispatch first
    int b = blockIdx.y, h = blockIdx.z;
    size_t hb = (size_t)h * 4 + b;
    __shared__ _Float16 KsH[64 * 64], KsL[64 * 64];
    __shared__ _Float16 Vs[64 * 64], Ps[64 * 64];
    int tid = threadIdx.x, lane = tid & 63, w = tid >> 6;
    int l15 = lane & 15, l4 = lane >> 4;
    int s0 = qt * 64;
    int srow = w * 16 + l15;
    int sg = s0 + srow;

    // Q frags: direct global load
    f16x8 qfH[2], qfL[2];
    #pragma unroll
    for (int ks = 0; ks < 2; ++ks) {
        size_t qa = (hb * 1024 + s0 + srow) * 64 + ks * 32 + l4 * 8;
        qfH[ks] = *(const f16x8*)&QbH[qa];
        qfL[ks] = *(const f16x8*)&QbL[qa];
    }
    // prologue: load tile 0 into regs
    f16x8 rkH[2], rkL[2], rv[2];
    #pragma unroll
    for (int rr = 0; rr < 2; ++rr) {
        int u = rr * 256 + tid, row = u >> 3, c8 = u & 7;
        size_t ki = (hb * 1024 + row) * 64 + c8 * 8;
        rkH[rr] = *(const f16x8*)&K2H[ki];
        rkL[rr] = *(const f16x8*)&K2L[ki];
        rv[rr]  = *(const f16x8*)&V2[(hb * 64 + row) * 1024 + c8 * 8];
    }

    float m = -__builtin_inff(), lsum = 0.f;
    f32x4 zero = {0.f, 0.f, 0.f, 0.f};
    f32x4 acc2[4] = {zero, zero, zero, zero};
    int ntile = qt + 1;

    for (int tt = 0; tt < ntile; ++tt) {
        int t0 = tt * 64;
        __syncthreads();                 // prev tile's LDS reads done
        #pragma unroll
        for (int rr = 0; rr < 2; ++rr) { // write current tile from regs
            int u = rr * 256 + tid, row = u >> 3, c8 = u & 7;
            int off = swzb(row, c8 * 16);
            *(f16x8*)((char*)KsH + off) = rkH[rr];
            *(f16x8*)((char*)KsL + off) = rkL[rr];
            *(f16x8*)((char*)Vs + off)  = rv[rr];
        }
        if (tt + 1 < ntile) {            // issue next-tile loads
            int t0n = t0 + 64;
            #pragma unroll
            for (int rr = 0; rr < 2; ++rr) {
                int u = rr * 256 + tid, row = u >> 3, c8 = u & 7;
                size_t ki = (hb * 1024 + t0n + row) * 64 + c8 * 8;
                rkH[rr] = *(const f16x8*)&K2H[ki];
                rkL[rr] = *(const f16x8*)&K2L[ki];
                rv[rr]  = *(const f16x8*)&V2[(hb * 64 + row) * 1024 + t0n + c8 * 8];
            }
        }
        __syncthreads();

        f32x4 z[4] = {zero, zero, zero, zero};
        __builtin_amdgcn_s_setprio(1);
        #pragma unroll
        for (int ks = 0; ks < 2; ++ks) {
            int kb = (ks * 32 + l4 * 8) * 2;
            #pragma unroll
            for (int f = 0; f < 4; ++f) {
                int trow = f * 16 + l15;
                f16x8 akH = *(const f16x8*)((char*)KsH + swzb(trow, kb));
                f16x8 akL = *(const f16x8*)((char*)KsL + swzb(trow, kb));
                z[f] = __builtin_amdgcn_mfma_f32_16x16x32_f16(akH, qfH[ks], z[f], 0, 0, 0);
                z[f] = __builtin_amdgcn_mfma_f32_16x16x32_f16(akH, qfL[ks], z[f], 0, 0, 0);
                z[f] = __builtin_amdgcn_mfma_f32_16x16x32_f16(akL, qfH[ks], z[f], 0, 0, 0);
            }
        }
        __builtin_amdgcn_s_setprio(0);
        // scale + causal mask + lane-local row max
        float mt = -__builtin_inff();
        #pragma unroll
        for (int f = 0; f < 4; ++f)
            #pragma unroll
            for (int r = 0; r < 4; ++r) {
                int tg = t0 + f * 16 + l4 * 4 + r;
                float val = z[f][r] * 0.125f;
                val = (tg > sg) ? -__builtin_inff() : val;
                z[f][r] = val;
                mt = fmaxf(mt, val);
            }
        mt = fmaxf(mt, __shfl_xor(mt, 16));
        mt = fmaxf(mt, __shfl_xor(mt, 32));
        float mn = fmaxf(m, mt);
        float corr = __expf(m - mn);
        float ps = 0.f;
        #pragma unroll
        for (int f = 0; f < 4; ++f)
            #pragma unroll
            for (int r = 0; r < 4; ++r) {
                float p = __expf(z[f][r] - mn);
                z[f][r] = p;
                ps += p;
            }
        ps += __shfl_xor(ps, 16);
        ps += __shfl_xor(ps, 32);
        lsum = lsum * corr + ps;
        m = mn;
        #pragma unroll
        for (int f = 0; f < 4; ++f) acc2[f] *= corr;

        // P^T -> Ps (wave-private rows, no barrier needed)
        #pragma unroll
        for (int f = 0; f < 4; ++f) {
            f16x4 pk = { (_Float16)z[f][0], (_Float16)z[f][1],
                         (_Float16)z[f][2], (_Float16)z[f][3] };
            *(f16x4*)((char*)Ps + swzb(srow, (f * 16 + l4 * 4) * 2)) = pk;
        }
        __builtin_amdgcn_s_setprio(1);
        #pragma unroll
        for (int ks = 0; ks < 2; ++ks) {
            int kb = (ks * 32 + l4 * 8) * 2;
            f16x8 bp = *(const f16x8*)((char*)Ps + swzb(srow, kb));
            #pragma unroll
            for (int f = 0; f < 4; ++f) {
                int dvrow = f * 16 + l15;
                f16x8 av = *(const f16x8*)((char*)Vs + swzb(dvrow, kb));
                acc2[f] = __builtin_amdgcn_mfma_f32_16x16x32_f16(av, bp, acc2[f], 0, 0, 0);
            }
        }
        __builtin_amdgcn_s_setprio(0);
    }

    float inv = 1.f / lsum;
    int sp = s0 + srow;
    int bprow = h >> 2;
    int spp = (h & 3) * 256 + b * 64 + (sp >> 4);
    int cb = (sp & 15) * 64;
    #pragma unroll
    for (int f = 0; f < 4; ++f) {
        int dv = f * 16 + l4 * 4;
        f16x4 o = { (_Float16)(acc2[f][0] * inv), (_Float16)(acc2[f][1] * inv),
                    (_Float16)(acc2[f][2] * inv), (_Float16)(acc2[f][3] * inv) };
        *(f16x4*)&CC[((size_t)bprow * 1024 + spp) * 1024 + cb + dv] = o;
    }
}

// ---------------------------------------------------------------------------
// Output projection: CC[4096][1024] @ WoT[1024][1024]^T -> out f32.
// m97 structure: 128x128 tile, BK=64, gload_lds, linear LDS.
// ---------------------------------------------------------------------------
__global__ __launch_bounds__(256) void gemm_out(
    const _Float16* __restrict__ A, const _Float16* __restrict__ BT,
    float* __restrict__ out) {
    __shared__ _Float16 As[128 * 64];
    __shared__ _Float16 Bs[128 * 64];
    int wg = ((int)blockIdx.x & 7) * 32 + ((int)blockIdx.x >> 3);
    int mt = wg >> 3, nt = wg & 7;
    int r0 = mt * 128, c0 = nt * 128;
    int tid = threadIdx.x, lane = tid & 63, w = tid >> 6;
    int wr = w >> 1, wc = w & 1;
    int l15 = lane & 15, l4 = lane >> 4;

    f32x4 zero = {0.f, 0.f, 0.f, 0.f};
    f32x4 acc[4][4];
    #pragma unroll
    for (int i = 0; i < 4; ++i)
        #pragma unroll
        for (int j = 0; j < 4; ++j) acc[i][j] = zero;

    for (int kt = 0; kt < 16; ++kt) {
        __syncthreads();
        #pragma unroll
        for (int rr = 0; rr < 4; ++rr) {
            int u = rr * 256 + tid;
            int row = u >> 3, c8 = u & 7;
            size_t ga = (size_t)(r0 + row) * 1024 + kt * 64 + c8 * 8;
            size_t gb = (size_t)(c0 + row) * 1024 + kt * 64 + c8 * 8;
            __builtin_amdgcn_global_load_lds(&A[ga],  &As[u * 8], 16, 0, 0);
            __builtin_amdgcn_global_load_lds(&BT[gb], &Bs[u * 8], 16, 0, 0);
        }
        __syncthreads();

        #pragma unroll
        for (int ks = 0; ks < 2; ++ks) {
            int kb = (ks * 32 + l4 * 8) * 2;
            f16x8 af[4], bf[4];
            #pragma unroll
            for (int f = 0; f < 4; ++f) {
                int ar = wr * 64 + f * 16 + l15;
                int br = wc * 64 + f * 16 + l15;
                af[f] = *(const f16x8*)((char*)As + ar * 128 + kb);
                bf[f] = *(const f16x8*)((char*)Bs + br * 128 + kb);
            }
            #pragma unroll
            for (int i = 0; i < 4; ++i)
                #pragma unroll
                for (int j = 0; j < 4; ++j)
                    acc[i][j] = __builtin_amdgcn_mfma_f32_16x16x32_f16(
                        af[i], bf[j], acc[i][j], 0, 0, 0);
        }
    }

    #pragma unroll
    for (int i = 0; i < 4; ++i) {
        int grow0 = r0 + wr * 64 + i * 16 + l4 * 4;
        #pragma unroll
        for (int j = 0; j < 4; ++j) {
            int gcol = c0 + wc * 64 + j * 16 + l15;
            #pragma unroll
            for (int r = 0; r < 4; ++r)
                out[(size_t)(grow0 + r) * 1024 + gcol] = acc[i][j][r];
        }
    }
}

// ---------------------------------------------------------------------------
extern "C" void kernel_launch(void* const* d_in, const int* in_sizes, int n_in,
                              void* d_out, int out_size, void* d_ws, size_t ws_size,
                              hipStream_t stream) {
    const float* emb = (const float*)d_in[0];
    const float* Wq  = (const float*)d_in[1];
    const float* Wk  = (const float*)d_in[2];
    const float* Wv  = (const float*)d_in[3];
    const float* Wo  = (const float*)d_in[4];
    float* out = (float*)d_out;

    // ws: 52 MB with aliasing (lifetimes checked against stream order)
    _Float16* embH = (_Float16*)d_ws;          // 4M f16   [K2H aliases later]
    _Float16* embL = embH + 4194304;           // 4M       [K2L aliases later]
    _Float16* WTh  = embL + 4194304;           // 3M       [CC aliases later]
    _Float16* WTl  = WTh + 3145728;            // 2M
    _Float16* WoT  = WTl + 2097152;            // 1M
    _Float16* QbH  = WoT + 1048576;            // 4M
    _Float16* QbL  = QbH + 4194304;            // 4M
    _Float16* V2   = QbL + 4194304;            // 4M  -> total 26M f16 = 52 MB
    _Float16* K2H  = embH;                     // alias: emb dead after gemm_v
    _Float16* K2L  = embL;
    _Float16* CC   = WTh;                      // alias: WT dead after gemm_v
    // kkT hi/lo parked in d_out (16 MB), dead before gemm_out writes it
    _Float16* kkTH = (_Float16*)d_out;
    _Float16* kkTL = kkTH + 4194304;

    prep     <<<3072, 256, 0, stream>>>(emb, Wq, Wk, Wv, Wo,
                                        embH, embL, WTh, WTl, WoT);
    gemm_qk  <<<512, 256, 0, stream>>>(embH, embL, WTh, WTl,
                                       QbH, QbL, kkTH, kkTL);
    gemm_v   <<<256, 256, 0, stream>>>(embH, WTh, V2);
    trans_k  <<<dim3(16, 64, 2), 256, 0, stream>>>(kkTH, kkTL, K2H, K2L);
    attn     <<<dim3(16, 4, 16), 256, 0, stream>>>(QbH, QbL, K2H, K2L, V2, CC);
    gemm_out <<<256, 256, 0, stream>>>(CC, WoT, out);
}